// Round 6
// baseline (224.309 us; speedup 1.0000x reference)
//
#include <hip/hip_runtime.h>
#include <hip/hip_bf16.h>

#define B_ 8
#define L_ 2048
#define D_ 256
#define BK 32
#define KSPLIT 2
#define KQ (L_/KSPLIT)         // 1024 keys per split
#define NIT (KQ/BK)            // 32 iterations
#define PSTR 40
#define NROW (B_*L_)           // 16384
#define NE ((size_t)B_*L_*D_)  // 4194304
#define THR 9.0f               // defer-max threshold: P <= e^9 ~ 8100, fp16-safe
#define MINIT (-1e30f)         // finite -inf substitute

typedef __attribute__((ext_vector_type(8))) _Float16 f16x8;
typedef __attribute__((ext_vector_type(4))) _Float16 hf4;
typedef __attribute__((ext_vector_type(4))) float f32x4;

#define MFMA16F(a,b,c) __builtin_amdgcn_mfma_f32_16x16x32_f16((a),(b),(c),0,0,0)
#define NEG_INF (-__builtin_inff())
#define GLL(src,dst) __builtin_amdgcn_global_load_lds( \
    (const __attribute__((address_space(1))) void*)(src), \
    (__attribute__((address_space(3))) void*)(dst), 16, 0, 0)

__device__ __forceinline__ f32x4 fmax4(f32x4 a, f32x4 b){
  f32x4 r;
  r[0]=fmaxf(a[0],b[0]); r[1]=fmaxf(a[1],b[1]);
  r[2]=fmaxf(a[2],b[2]); r[3]=fmaxf(a[3],b[3]);
  return r;
}

// ---- prep: fp32 x -> fp16 x16 (row-major) + vtl (pre-tiled swizzled V^T) ----
// Also zeroes the split-K combine tickets (one per (b, q-block)).
__global__ void prep_k(const float* __restrict__ x,
                       _Float16* __restrict__ x16,
                       _Float16* __restrict__ vtl,
                       int* __restrict__ ticket){
  __shared__ _Float16 T[64][258];
  const int t = threadIdx.x;
  const int l0 = blockIdx.x*64, b = blockIdx.y;
  if (t == 0) ticket[b*(L_/64) + blockIdx.x] = 0;
  const int r = t>>5, c = (t&31)*8;
  #pragma unroll
  for (int p=0;p<8;++p){
    int row = r + p*8;
    size_t idx = ((size_t)(b*L_ + l0 + row))*D_ + c;
    float4 v0 = *(const float4*)(x + idx);
    float4 v1 = *(const float4*)(x + idx + 4);
    f16x8 h;
    h[0]=(_Float16)v0.x; h[1]=(_Float16)v0.y; h[2]=(_Float16)v0.z; h[3]=(_Float16)v0.w;
    h[4]=(_Float16)v1.x; h[5]=(_Float16)v1.y; h[6]=(_Float16)v1.z; h[7]=(_Float16)v1.w;
    *(f16x8*)(x16 + idx) = h;
    #pragma unroll
    for (int j=0;j<8;++j) T[row][c+j] = h[j];
  }
  __syncthreads();
  _Float16* vb = vtl + ((size_t)(b*64 + blockIdx.x*2))*8192;
  #pragma unroll
  for (int i=0;i<8;++i){
    int n = t + 256*i;
    int q = n & 1023, tile = n>>10;
    int d = q>>2, ph = q&3;
    int kc = ph ^ ((d>>1)&3);
    int k0 = tile*32 + kc*8;
    f16x8 h;
    #pragma unroll
    for (int j=0;j<8;++j) h[j] = T[k0+j][d];
    *(f16x8*)(vb + (size_t)n*8) = h;
  }
}

// ---- single-pass flash, QBLK=16, one-tile P/V pipeline, fused combine ----
// Iteration t: QK(t) -> PV(t-1) -> softmax(t) -> write sP[t&1] -> barrier.
// After the K-loop each block writes split partials; the LAST z-block of a
// (b, q-block) pair (ticket) combines both splits inline (reusing sK as the
// transpose buffer), eliminating the separate combine dispatch + boundary.
__launch_bounds__(256, 2)
__global__ void flash_k(const _Float16* __restrict__ x16,
                        const _Float16* __restrict__ vtl,
                        const int* __restrict__ mask,
                        _Float16* __restrict__ oall,
                        float* __restrict__ mll,
                        float* __restrict__ mm,
                        float* __restrict__ out,
                        int* __restrict__ ticket){
  __shared__ __attribute__((aligned(16))) _Float16 sK[2][8192];     // 32 KB
  __shared__ __attribute__((aligned(16))) _Float16 sV[2][8192];     // 32 KB
  __shared__ __attribute__((aligned(16))) _Float16 sP[2][4][16*PSTR];// 10 KB
  __shared__ int who;

  const int tid  = threadIdx.x;
  const int wave = tid >> 6, lane = tid & 63;
  const int quad = lane >> 4, l16 = lane & 15;
  const int b = blockIdx.y, z = blockIdx.z;
  const int q0w = blockIdx.x*64 + wave*16;
  const int sw = l16 & 7, vsw = (l16>>1)&3;

  f16x8 qh[8];
  {
    const _Float16* qr = x16 + ((size_t)(b*L_ + q0w + l16))*D_;
    #pragma unroll
    for (int ks=0; ks<8; ++ks)
      qh[ks] = *(const f16x8*)(qr + ks*32 + quad*8);
  }
  unsigned long long mb = 0;
  {
    const int* mrow = mask + b*L_ + z*KQ;
    #pragma unroll
    for (int j=0;j<64;++j)
      mb |= (unsigned long long)(mrow[j*16 + l16] ? 1u : 0u) << j;
  }

  f32x4 M = (f32x4){MINIT, MINIT, MINIT, MINIT};

  unsigned kof[4], vof[4], dof[4];
  #pragma unroll
  for (int i=0;i<4;++i){
    int c = (wave + i*4)*64 + lane;
    int r = c>>5, pk = c&31;
    kof[i] = (unsigned)(r*512 + ((pk ^ (r&7))*16));
    vof[i] = (unsigned)(c*16);
    dof[i] = (unsigned)((wave + i*4)*1024);
  }
  const char* kbase = (const char*)x16 + ((size_t)b*L_ + (size_t)z*KQ)*(D_*2);
  const char* vbase = (const char*)vtl + ((size_t)(b*64 + z*32))*16384;

  // prologue: K_0 only (V_0 is staged at the top of iter 0)
  #pragma unroll
  for (int i=0;i<4;++i) GLL(kbase + kof[i], (char*)sK[0] + dof[i]);

  f32x4 O[16], Osum;
  #pragma unroll
  for (int i=0;i<16;i++) O[i] = (f32x4){0.f,0.f,0.f,0.f};
  Osum = (f32x4){0.f,0.f,0.f,0.f};
  f16x8 ones;
  #pragma unroll
  for (int j=0;j<8;++j) ones[j] = (_Float16)1.0f;

  __syncthreads();   // K_0 visible

  for (int it=0; it<NIT; ++it){
    // ---- stage K_{t+1} and V_t ----
    if (it+1 < NIT){
      const char* kb2 = kbase + (size_t)(it+1)*16384;
      char* kd = (char*)sK[(it+1)&1];
      #pragma unroll
      for (int i=0;i<4;++i) GLL(kb2 + kof[i], kd + dof[i]);
    }
    {
      const char* vb2 = vbase + (size_t)it*16384;
      char* vd = (char*)sV[it&1];
      #pragma unroll
      for (int i=0;i<4;++i) GLL(vb2 + vof[i], vd + dof[i]);
    }
    const _Float16* kb = sK[it&1];

    // ---- S = Q·K^T (tile t) ----
    f32x4 S[2];
    S[0]=(f32x4){0,0,0,0}; S[1]=(f32x4){0,0,0,0};
    #pragma unroll
    for (int ks=0; ks<8; ++ks){
      f16x8 b0 = *(const f16x8*)(kb + (     l16)*256 + (((ks*4+quad)^sw)*8));
      f16x8 b1 = *(const f16x8*)(kb + (16 + l16)*256 + (((ks*4+quad)^sw)*8));
      S[0] = MFMA16F(qh[ks], b0, S[0]);
      S[1] = MFMA16F(qh[ks], b1, S[1]);
    }

    // ---- PV (tile t-1): operands ready since last barrier ----
    if (it > 0){
      const _Float16* vb = sV[(it-1)&1];
      f16x8 pf = *(const f16x8*)(&sP[(it-1)&1][wave][l16*PSTR + quad*8]);
      #pragma unroll
      for (int vt=0; vt<16; ++vt){
        f16x8 bv = *(const f16x8*)(vb + (vt*16+l16)*32 + ((quad^vsw)*8));
        O[vt] = MFMA16F(pf, bv, O[vt]);
      }
      Osum = MFMA16F(pf, ones, Osum);
    }

    // ---- diag zero, then key padding mask (tile t) ----
    {
      const int d0 = q0w - (z*KQ + it*BK);
      if ((unsigned)d0 < 32u){
        const int ntd = d0 >> 4;
        #pragma unroll
        for (int r=0;r<4;++r)
          S[ntd][r] = (l16 == quad*4+r) ? 0.0f : S[ntd][r];
      }
    }
    {
      const unsigned mw = (unsigned)(mb >> (unsigned)(it*2));
      const float mk0 = (mw & 1u) ? NEG_INF : 0.0f;
      const float mk1 = (mw & 2u) ? NEG_INF : 0.0f;
      #pragma unroll
      for (int r=0;r<4;++r){ S[0][r] += mk0; S[1][r] += mk1; }
    }

    // ---- defer-max check; rescale covers all tiles < t (PV t-1 done) ----
    {
      f32x4 t = fmax4(S[0], S[1]);
      int ok = 1;
      #pragma unroll
      for (int r=0;r<4;++r) ok &= (t[r] <= M[r] + THR);
      if (!__all(ok)){
        #pragma unroll
        for (int off=1; off<16; off<<=1){
          f32x4 o;
          o[0]=__shfl_xor(t[0],off); o[1]=__shfl_xor(t[1],off);
          o[2]=__shfl_xor(t[2],off); o[3]=__shfl_xor(t[3],off);
          t = fmax4(t,o);
        }
        f32x4 mn = fmax4(M, t);
        float sc[4];
        #pragma unroll
        for (int r=0;r<4;++r) sc[r] = __expf(M[r] - mn[r]);
        #pragma unroll
        for (int vt=0; vt<16; ++vt){
          #pragma unroll
          for (int r=0;r<4;++r) O[vt][r] *= sc[r];
        }
        #pragma unroll
        for (int r=0;r<4;++r) Osum[r] *= sc[r];
        M = mn;
      }
    }

    // ---- P = exp(S - M) -> sP[t&1]; consumed next iteration ----
    #pragma unroll
    for (int r=0;r<4;++r){
      const int row = quad*4 + r;
      sP[it&1][wave][row*PSTR +      l16] = (_Float16)__expf(S[0][r] - M[r]);
      sP[it&1][wave][row*PSTR + 16 + l16] = (_Float16)__expf(S[1][r] - M[r]);
    }

    __syncthreads();   // sP/sV(t) visible for t+1; staging drained
  }

  // ---- drain: PV for the last tile ----
  {
    const _Float16* vb = sV[(NIT-1)&1];
    f16x8 pf = *(const f16x8*)(&sP[(NIT-1)&1][wave][l16*PSTR + quad*8]);
    #pragma unroll
    for (int vt=0; vt<16; ++vt){
      f16x8 bv = *(const f16x8*)(vb + (vt*16+l16)*32 + ((quad^vsw)*8));
      O[vt] = MFMA16F(pf, bv, O[vt]);
    }
    Osum = MFMA16F(pf, ones, Osum);
  }

  // ---- write split partials: fragment-major fp16 O' + l + m ----
  {
    const int u = b*(L_/16) + blockIdx.x*4 + wave;
    _Float16* ob = oall + (size_t)z*NE + (size_t)u*4096;
    #pragma unroll
    for (int vt=0; vt<16; ++vt){
      hf4 hh;
      #pragma unroll
      for (int r=0;r<4;++r) hh[r] = (_Float16)O[vt][r];
      *(hf4*)(ob + vt*256 + lane*4) = hh;
    }
    if (l16 == 0){
      const int row = u*16 + quad*4;
      #pragma unroll
      for (int r=0;r<4;++r){
        mll[z*NROW + row + r] = Osum[r];
        mm [z*NROW + row + r] = M[r];
      }
    }
  }

  // ---- split-K ticket: last-arriving z-block combines its 64 rows ----
  __threadfence();                    // publish partials device-wide
  if (tid == 0) who = atomicAdd(&ticket[b*(L_/64) + blockIdx.x], 1);
  __syncthreads();
  if (who != KSPLIT-1) return;        // block-uniform
  __threadfence();                    // acquire other split's writes

  {
    float (*T2)[260] = reinterpret_cast<float(*)[260]>(&sK[0][0]); // reuse 16.6KB
    const int quad2 = (tid>>4)&3, l162 = tid&15;
    #pragma unroll 1
    for (int g=0; g<4; ++g){
      const int u = b*(L_/16) + blockIdx.x*4 + g;
      const int row0 = u*16 + quad2*4;

      f32x4 mz0 = *(const f32x4*)(mm  + row0);
      f32x4 mz1 = *(const f32x4*)(mm  + NROW + row0);
      f32x4 lz0 = *(const f32x4*)(mll + row0);
      f32x4 lz1 = *(const f32x4*)(mll + NROW + row0);
      f32x4 ms = fmax4(mz0, mz1);
      float s0[4], s1[4], inv[4];
      #pragma unroll
      for (int r=0;r<4;++r){
        s0[r] = __expf(mz0[r] - ms[r]);
        s1[r] = __expf(mz1[r] - ms[r]);
        inv[r] = 1.0f/(s0[r]*lz0[r] + s1[r]*lz1[r]);
      }

      #pragma unroll
      for (int i=0;i<4;++i){
        const int f = tid + 256*i;
        const int vt = f>>6;
        hf4 v0 = *(const hf4*)(oall + (size_t)u*4096 + (size_t)f*4);
        hf4 v1 = *(const hf4*)(oall + NE + (size_t)u*4096 + (size_t)f*4);
        #pragma unroll
        for (int r=0;r<4;++r)
          T2[quad2*4+r][vt*16+l162] =
            (s0[r]*(float)v0[r] + s1[r]*(float)v1[r]) * inv[r];
      }
      __syncthreads();
      #pragma unroll
      for (int p=0;p<4;++p){
        const int row = (tid>>6) + p*4, col = (tid&63)*4;
        float4 vv = *(const float4*)&T2[row][col];
        *(float4*)(out + ((size_t)u*16 + row)*D_ + col) = vv;
      }
      __syncthreads();   // T2 reuse safe for next g
    }
  }
}

extern "C" void kernel_launch(void* const* d_in, const int* in_sizes, int n_in,
                              void* d_out, int out_size, void* d_ws, size_t ws_size,
                              hipStream_t stream) {
  const float* x    = (const float*)d_in[0];
  const int*   mask = (const int*)d_in[1];
  float*       out  = (float*)d_out;

  _Float16* x16  = (_Float16*)d_ws;
  _Float16* vtl  = x16 + NE;
  _Float16* oall = vtl + NE;                       // KSPLIT*NE fp16
  float*    mll  = (float*)(oall + (size_t)KSPLIT*NE);
  float*    mm   = mll + (size_t)KSPLIT*NROW;
  int*      tick = (int*)(mm + (size_t)KSPLIT*NROW);   // B*(L/64) = 256 ints

  prep_k <<<dim3(L_/64, B_), dim3(256), 0, stream>>>(x, x16, vtl, tick);
  flash_k<<<dim3(L_/64, B_, KSPLIT), dim3(256), 0, stream>>>(
      x16, vtl, mask, oall, mll, mm, out, tick);
}

// Round 7
// 151.291 us; speedup vs baseline: 1.4826x; 1.4826x over previous
//
#include <hip/hip_runtime.h>
#include <hip/hip_bf16.h>

#define B_ 8
#define L_ 2048
#define D_ 256
#define BK 32
#define KSPLIT 2
#define KQ (L_/KSPLIT)         // 1024 keys per split
#define NIT (KQ/BK)            // 32 iterations
#define PSTR 40
#define NROW (B_*L_)           // 16384
#define NE ((size_t)B_*L_*D_)  // 4194304
#define THR 13.0f              // defer-max threshold, log2 domain: P <= 2^13, fp16-safe
#define MINIT (-1e30f)         // finite -inf substitute
#define LOG2E_F 1.44269504f

typedef __attribute__((ext_vector_type(8))) _Float16 f16x8;
typedef __attribute__((ext_vector_type(4))) _Float16 hf4;
typedef __attribute__((ext_vector_type(4))) float f32x4;

#define MFMA16F(a,b,c) __builtin_amdgcn_mfma_f32_16x16x32_f16((a),(b),(c),0,0,0)
#define NEG_INF (-__builtin_inff())
#define GLL(src,dst) __builtin_amdgcn_global_load_lds( \
    (const __attribute__((address_space(1))) void*)(src), \
    (__attribute__((address_space(3))) void*)(dst), 16, 0, 0)

__device__ __forceinline__ f32x4 fmax4(f32x4 a, f32x4 b){
  f32x4 r;
  r[0]=fmaxf(a[0],b[0]); r[1]=fmaxf(a[1],b[1]);
  r[2]=fmaxf(a[2],b[2]); r[3]=fmaxf(a[3],b[3]);
  return r;
}

// ---- prep: fp32 x -> fp16 x16 (row-major) + vtl (pre-tiled swizzled V^T) ----
__global__ void prep_k(const float* __restrict__ x,
                       _Float16* __restrict__ x16,
                       _Float16* __restrict__ vtl){
  __shared__ _Float16 T[64][258];
  const int t = threadIdx.x;
  const int l0 = blockIdx.x*64, b = blockIdx.y;
  const int r = t>>5, c = (t&31)*8;
  #pragma unroll
  for (int p=0;p<8;++p){
    int row = r + p*8;
    size_t idx = ((size_t)(b*L_ + l0 + row))*D_ + c;
    float4 v0 = *(const float4*)(x + idx);
    float4 v1 = *(const float4*)(x + idx + 4);
    f16x8 h;
    h[0]=(_Float16)v0.x; h[1]=(_Float16)v0.y; h[2]=(_Float16)v0.z; h[3]=(_Float16)v0.w;
    h[4]=(_Float16)v1.x; h[5]=(_Float16)v1.y; h[6]=(_Float16)v1.z; h[7]=(_Float16)v1.w;
    *(f16x8*)(x16 + idx) = h;
    #pragma unroll
    for (int j=0;j<8;++j) T[row][c+j] = h[j];
  }
  __syncthreads();
  _Float16* vb = vtl + ((size_t)(b*64 + blockIdx.x*2))*8192;
  #pragma unroll
  for (int i=0;i<8;++i){
    int n = t + 256*i;
    int q = n & 1023, tile = n>>10;
    int d = q>>2, ph = q&3;
    int kc = ph ^ ((d>>1)&3);
    int k0 = tile*32 + kc*8;
    f16x8 h;
    #pragma unroll
    for (int j=0;j<8;++j) h[j] = T[k0+j][d];
    *(f16x8*)(vb + (size_t)n*8) = h;
  }
}

// ---- single-pass flash, QBLK=16, 8-wave blocks sharing one K/V dbuf ----
// Two 4-wave blocks per CU (r5) become one 8-wave block: same 2 waves/SIMD,
// same per-wave LDS reads, but staging (GLL) and K/V HBM fetch per CU halve.
// LDS 84KB -> exactly 1 block/CU; grid 256 = 256 CUs, zero tail.
// Iteration t: QK(t) -> PV(t-1) -> softmax(t) -> write sP[t&1] -> barrier.
// Softmax runs in exp2 domain: Q pre-scaled by log2e at load, exp2f直接,
// mm/combine in log2 domain (identical math, 16 fewer muls/iter/lane).
__launch_bounds__(512, 2)
__global__ void flash_k(const _Float16* __restrict__ x16,
                        const _Float16* __restrict__ vtl,
                        const int* __restrict__ mask,
                        _Float16* __restrict__ oall,
                        float* __restrict__ mll,
                        float* __restrict__ mm){
  __shared__ __attribute__((aligned(16))) _Float16 sK[2][8192];     // 32 KB
  __shared__ __attribute__((aligned(16))) _Float16 sV[2][8192];     // 32 KB
  __shared__ __attribute__((aligned(16))) _Float16 sP[2][8][16*PSTR];// 20 KB

  const int tid  = threadIdx.x;
  const int wave = tid >> 6, lane = tid & 63;
  const int quad = lane >> 4, l16 = lane & 15;
  const int b = blockIdx.y, z = blockIdx.z;
  const int q0w = blockIdx.x*128 + wave*16;
  const int sw = l16 & 7, vsw = (l16>>1)&3;

  f16x8 qh[8];
  {
    const _Float16* qr = x16 + ((size_t)(b*L_ + q0w + l16))*D_;
    const _Float16 l2e = (_Float16)LOG2E_F;
    #pragma unroll
    for (int ks=0; ks<8; ++ks){
      f16x8 h = *(const f16x8*)(qr + ks*32 + quad*8);
      #pragma unroll
      for (int j=0;j<8;++j) h[j] = h[j] * l2e;   // log2-domain scores
      qh[ks] = h;
    }
  }
  unsigned long long mb = 0;
  {
    const int* mrow = mask + b*L_ + z*KQ;
    #pragma unroll
    for (int j=0;j<64;++j)
      mb |= (unsigned long long)(mrow[j*16 + l16] ? 1u : 0u) << j;
  }

  f32x4 M = (f32x4){MINIT, MINIT, MINIT, MINIT};

  // staging: 16 chunks of 1KB; wave w covers chunks {2w, 2w+1}
  unsigned kof[2], vof[2], dof[2];
  #pragma unroll
  for (int i=0;i<2;++i){
    int c = (wave*2 + i)*64 + lane;
    int r = c>>5, pk = c&31;
    kof[i] = (unsigned)(r*512 + ((pk ^ (r&7))*16));
    vof[i] = (unsigned)(c*16);
    dof[i] = (unsigned)((wave*2 + i)*1024);
  }
  const char* kbase = (const char*)x16 + ((size_t)b*L_ + (size_t)z*KQ)*(D_*2);
  const char* vbase = (const char*)vtl + ((size_t)(b*64 + z*32))*16384;

  // prologue: K_0 only (V_0 is staged at the top of iter 0)
  #pragma unroll
  for (int i=0;i<2;++i) GLL(kbase + kof[i], (char*)sK[0] + dof[i]);

  f32x4 O[16], Osum;
  #pragma unroll
  for (int i=0;i<16;i++) O[i] = (f32x4){0.f,0.f,0.f,0.f};
  Osum = (f32x4){0.f,0.f,0.f,0.f};
  f16x8 ones;
  #pragma unroll
  for (int j=0;j<8;++j) ones[j] = (_Float16)1.0f;

  __syncthreads();   // K_0 visible

  for (int it=0; it<NIT; ++it){
    // ---- stage K_{t+1} and V_t ----
    if (it+1 < NIT){
      const char* kb2 = kbase + (size_t)(it+1)*16384;
      char* kd = (char*)sK[(it+1)&1];
      #pragma unroll
      for (int i=0;i<2;++i) GLL(kb2 + kof[i], kd + dof[i]);
    }
    {
      const char* vb2 = vbase + (size_t)it*16384;
      char* vd = (char*)sV[it&1];
      #pragma unroll
      for (int i=0;i<2;++i) GLL(vb2 + vof[i], vd + dof[i]);
    }
    const _Float16* kb = sK[it&1];

    // ---- S = Q·K^T (tile t, log2 domain) ----
    f32x4 S[2];
    S[0]=(f32x4){0,0,0,0}; S[1]=(f32x4){0,0,0,0};
    #pragma unroll
    for (int ks=0; ks<8; ++ks){
      f16x8 b0 = *(const f16x8*)(kb + (     l16)*256 + (((ks*4+quad)^sw)*8));
      f16x8 b1 = *(const f16x8*)(kb + (16 + l16)*256 + (((ks*4+quad)^sw)*8));
      S[0] = MFMA16F(qh[ks], b0, S[0]);
      S[1] = MFMA16F(qh[ks], b1, S[1]);
    }

    // ---- PV (tile t-1): operands ready since last barrier ----
    if (it > 0){
      const _Float16* vb = sV[(it-1)&1];
      f16x8 pf = *(const f16x8*)(&sP[(it-1)&1][wave][l16*PSTR + quad*8]);
      #pragma unroll
      for (int vt=0; vt<16; ++vt){
        f16x8 bv = *(const f16x8*)(vb + (vt*16+l16)*32 + ((quad^vsw)*8));
        O[vt] = MFMA16F(pf, bv, O[vt]);
      }
      Osum = MFMA16F(pf, ones, Osum);
    }

    // ---- diag zero (score 0 -> log2 score 0), then key padding mask ----
    {
      const int d0 = q0w - (z*KQ + it*BK);
      if ((unsigned)d0 < 32u){
        const int ntd = d0 >> 4;
        #pragma unroll
        for (int r=0;r<4;++r)
          S[ntd][r] = (l16 == quad*4+r) ? 0.0f : S[ntd][r];
      }
    }
    {
      const unsigned mw = (unsigned)(mb >> (unsigned)(it*2));
      const float mk0 = (mw & 1u) ? NEG_INF : 0.0f;
      const float mk1 = (mw & 2u) ? NEG_INF : 0.0f;
      #pragma unroll
      for (int r=0;r<4;++r){ S[0][r] += mk0; S[1][r] += mk1; }
    }

    // ---- defer-max check; rescale covers all tiles < t (PV t-1 done) ----
    {
      f32x4 t = fmax4(S[0], S[1]);
      int ok = 1;
      #pragma unroll
      for (int r=0;r<4;++r) ok &= (t[r] <= M[r] + THR);
      if (!__all(ok)){
        #pragma unroll
        for (int off=1; off<16; off<<=1){
          f32x4 o;
          o[0]=__shfl_xor(t[0],off); o[1]=__shfl_xor(t[1],off);
          o[2]=__shfl_xor(t[2],off); o[3]=__shfl_xor(t[3],off);
          t = fmax4(t,o);
        }
        f32x4 mn = fmax4(M, t);
        float sc[4];
        #pragma unroll
        for (int r=0;r<4;++r) sc[r] = exp2f(M[r] - mn[r]);
        #pragma unroll
        for (int vt=0; vt<16; ++vt){
          #pragma unroll
          for (int r=0;r<4;++r) O[vt][r] *= sc[r];
        }
        #pragma unroll
        for (int r=0;r<4;++r) Osum[r] *= sc[r];
        M = mn;
      }
    }

    // ---- P = 2^(S - M) -> sP[t&1]; consumed next iteration ----
    #pragma unroll
    for (int r=0;r<4;++r){
      const int row = quad*4 + r;
      sP[it&1][wave][row*PSTR +      l16] = (_Float16)exp2f(S[0][r] - M[r]);
      sP[it&1][wave][row*PSTR + 16 + l16] = (_Float16)exp2f(S[1][r] - M[r]);
    }

    __syncthreads();   // sP/sV(t) visible for t+1; staging drained
  }

  // ---- drain: PV for the last tile ----
  {
    const _Float16* vb = sV[(NIT-1)&1];
    f16x8 pf = *(const f16x8*)(&sP[(NIT-1)&1][wave][l16*PSTR + quad*8]);
    #pragma unroll
    for (int vt=0; vt<16; ++vt){
      f16x8 bv = *(const f16x8*)(vb + (vt*16+l16)*32 + ((quad^vsw)*8));
      O[vt] = MFMA16F(pf, bv, O[vt]);
    }
    Osum = MFMA16F(pf, ones, Osum);
  }

  // ---- epilogue: fragment-major fp16 partial O' + partial l + running m ----
  {
    const int u = b*(L_/16) + blockIdx.x*8 + wave;
    _Float16* ob = oall + (size_t)z*NE + (size_t)u*4096;
    #pragma unroll
    for (int vt=0; vt<16; ++vt){
      hf4 hh;
      #pragma unroll
      for (int r=0;r<4;++r) hh[r] = (_Float16)O[vt][r];
      *(hf4*)(ob + vt*256 + lane*4) = hh;
    }
    if (l16 == 0){
      const int row = u*16 + quad*4;
      #pragma unroll
      for (int r=0;r<4;++r){
        mll[z*NROW + row + r] = Osum[r];
        mm [z*NROW + row + r] = M[r];        // log2 domain
      }
    }
  }
}

// ---- combine: out = (sum_z 2^{m_z-m*} O'_z) / (sum_z 2^{m_z-m*} l_z) ----
__global__ void combine_k(float* __restrict__ out,
                          const _Float16* __restrict__ oall,
                          const float* __restrict__ mll,
                          const float* __restrict__ mm){
  __shared__ float T2[16][260];
  const int t = threadIdx.x, u = blockIdx.x;
  const int quad = (t>>4)&3, l16 = t&15;
  const int row0 = u*16 + quad*4;

  f32x4 mz[KSPLIT], lz[KSPLIT];
  #pragma unroll
  for (int zc=0; zc<KSPLIT; ++zc){
    mz[zc] = *(const f32x4*)(mm  + zc*NROW + row0);
    lz[zc] = *(const f32x4*)(mll + zc*NROW + row0);
  }
  f32x4 ms = mz[0];
  #pragma unroll
  for (int zc=1; zc<KSPLIT; ++zc) ms = fmax4(ms, mz[zc]);

  float sc[KSPLIT][4];
  f32x4 den = (f32x4){0.f,0.f,0.f,0.f};
  #pragma unroll
  for (int zc=0; zc<KSPLIT; ++zc){
    #pragma unroll
    for (int r=0;r<4;++r){
      sc[zc][r] = exp2f(mz[zc][r] - ms[r]);
      den[r] += sc[zc][r] * lz[zc][r];
    }
  }
  float inv[4];
  #pragma unroll
  for (int r=0;r<4;++r) inv[r] = 1.0f/den[r];

  #pragma unroll
  for (int i=0;i<4;++i){
    const int f = t + 256*i;
    const int vt = f>>6;
    float acc[4] = {0.f,0.f,0.f,0.f};
    #pragma unroll
    for (int zc=0; zc<KSPLIT; ++zc){
      hf4 v = *(const hf4*)(oall + (size_t)zc*NE + (size_t)u*4096 + (size_t)f*4);
      #pragma unroll
      for (int r=0;r<4;++r) acc[r] += sc[zc][r] * (float)v[r];
    }
    #pragma unroll
    for (int r=0;r<4;++r) T2[quad*4+r][vt*16+l16] = acc[r]*inv[r];
  }
  __syncthreads();
  #pragma unroll
  for (int p=0;p<4;++p){
    const int row = (t>>6) + p*4, col = (t&63)*4;
    float4 vv = *(const float4*)&T2[row][col];
    *(float4*)(out + ((size_t)u*16 + row)*D_ + col) = vv;
  }
}

extern "C" void kernel_launch(void* const* d_in, const int* in_sizes, int n_in,
                              void* d_out, int out_size, void* d_ws, size_t ws_size,
                              hipStream_t stream) {
  const float* x    = (const float*)d_in[0];
  const int*   mask = (const int*)d_in[1];
  float*       out  = (float*)d_out;

  _Float16* x16  = (_Float16*)d_ws;
  _Float16* vtl  = x16 + NE;
  _Float16* oall = vtl + NE;                       // KSPLIT*NE fp16
  float*    mll  = (float*)(oall + (size_t)KSPLIT*NE);
  float*    mm   = mll + (size_t)KSPLIT*NROW;

  prep_k   <<<dim3(L_/64, B_), dim3(256), 0, stream>>>(x, x16, vtl);
  flash_k  <<<dim3(L_/128, B_, KSPLIT), dim3(512), 0, stream>>>(x16, vtl, mask, oall, mll, mm);
  combine_k<<<dim3(NROW/16), dim3(256), 0, stream>>>(out, oall, mll, mm);
}

// Round 8
// 148.416 us; speedup vs baseline: 1.5114x; 1.0194x over previous
//
#include <hip/hip_runtime.h>
#include <hip/hip_bf16.h>

#define B_ 8
#define L_ 2048
#define D_ 256
#define BK 32
#define KSPLIT 2
#define KQ (L_/KSPLIT)         // 1024 keys per split
#define NIT (KQ/BK)            // 32 iterations
#define PSTR 40
#define NROW (B_*L_)           // 16384
#define NE ((size_t)B_*L_*D_)  // 4194304
#define THR 13.0f              // defer-max threshold, log2 domain (~e^9), fp16-safe
#define MINIT (-1e30f)         // finite -inf substitute
#define LOG2E_F 1.44269504f

typedef __attribute__((ext_vector_type(8))) _Float16 f16x8;
typedef __attribute__((ext_vector_type(4))) _Float16 hf4;
typedef __attribute__((ext_vector_type(4))) float f32x4;

#define MFMA16F(a,b,c) __builtin_amdgcn_mfma_f32_16x16x32_f16((a),(b),(c),0,0,0)
#define NEG_INF (-__builtin_inff())
#define GLL(src,dst) __builtin_amdgcn_global_load_lds( \
    (const __attribute__((address_space(1))) void*)(src), \
    (__attribute__((address_space(3))) void*)(dst), 16, 0, 0)

__device__ __forceinline__ f32x4 fmax4(f32x4 a, f32x4 b){
  f32x4 r;
  r[0]=fmaxf(a[0],b[0]); r[1]=fmaxf(a[1],b[1]);
  r[2]=fmaxf(a[2],b[2]); r[3]=fmaxf(a[3],b[3]);
  return r;
}

// ---- prep v2: fp32 x -> fp16 x16 + vtl (pre-tiled swizzled V^T) ----
// 32-key tiles: grid (64, B) = 512 blocks (2 blocks/CU, was 1 at 1 wave/SIMD).
// LDS staging vectorized: 4 ds_write_b128/thread (was 64 ds_write_b16).
// Column gather keeps 32 scalar reads/thread; stride 258 fp16 => per-j bank
// step = 129 dwords % 32 = 1, conflict-light. Layouts bit-identical to v1:
// vtl[(b*64 + tIdx)*8192 + q*8 + j] = x16[b, tIdx*32 + kc*8 + j, d].
__global__ void prep_k(const float* __restrict__ x,
                       _Float16* __restrict__ x16,
                       _Float16* __restrict__ vtl){
  __shared__ _Float16 T[32][258];
  const int t = threadIdx.x;
  const int tIdx = blockIdx.x;          // 32-key tile, 0..63
  const int b = blockIdx.y;
  const int l0 = tIdx*32;

  #pragma unroll
  for (int i=0;i<4;++i){
    const int n8 = t + 256*i;           // 8-float group, 0..1023
    const int row = n8>>5;              // 0..31
    const int c   = (n8&31)*8;          // 0..248
    size_t idx = ((size_t)(b*L_ + l0 + row))*D_ + c;
    float4 v0 = *(const float4*)(x + idx);
    float4 v1 = *(const float4*)(x + idx + 4);
    f16x8 h;
    h[0]=(_Float16)v0.x; h[1]=(_Float16)v0.y; h[2]=(_Float16)v0.z; h[3]=(_Float16)v0.w;
    h[4]=(_Float16)v1.x; h[5]=(_Float16)v1.y; h[6]=(_Float16)v1.z; h[7]=(_Float16)v1.w;
    *(f16x8*)(x16 + idx) = h;
    *(f16x8*)(&T[row][c]) = h;
  }
  __syncthreads();

  _Float16* vb = vtl + ((size_t)(b*64 + tIdx))*8192;
  #pragma unroll
  for (int i=0;i<4;++i){
    const int q = t + 256*i;            // 0..1023
    const int d = q>>2, ph = q&3;
    const int kc = ph ^ ((d>>1)&3);
    const int k0 = kc*8;
    f16x8 h;
    #pragma unroll
    for (int j=0;j<8;++j) h[j] = T[k0+j][d];
    *(f16x8*)(vb + (size_t)q*8) = h;
  }
}

// ---- single-pass flash, QBLK=16, one-tile P/V pipeline (r5 structure) ----
// exp2 domain: Q pre-scaled by log2e; all exponentials are raw v_exp_f32.
// Iteration t: QK(t) -> PV(t-1) -> softmax(t) -> write sP[t&1] -> barrier.
__launch_bounds__(256, 2)
__global__ void flash_k(const _Float16* __restrict__ x16,
                        const _Float16* __restrict__ vtl,
                        const int* __restrict__ mask,
                        _Float16* __restrict__ oall,
                        float* __restrict__ mll,
                        float* __restrict__ mm){
  __shared__ __attribute__((aligned(16))) _Float16 sK[2][8192];     // 32 KB
  __shared__ __attribute__((aligned(16))) _Float16 sV[2][8192];     // 32 KB
  __shared__ __attribute__((aligned(16))) _Float16 sP[2][4][16*PSTR];// 10 KB

  const int tid  = threadIdx.x;
  const int wave = tid >> 6, lane = tid & 63;
  const int quad = lane >> 4, l16 = lane & 15;
  const int b = blockIdx.y, z = blockIdx.z;
  const int q0w = blockIdx.x*64 + wave*16;
  const int sw = l16 & 7, vsw = (l16>>1)&3;

  f16x8 qh[8];
  {
    const _Float16* qr = x16 + ((size_t)(b*L_ + q0w + l16))*D_;
    const _Float16 l2e = (_Float16)LOG2E_F;
    #pragma unroll
    for (int ks=0; ks<8; ++ks){
      f16x8 h = *(const f16x8*)(qr + ks*32 + quad*8);
      #pragma unroll
      for (int j=0;j<8;++j) h[j] = h[j] * l2e;   // log2-domain scores
      qh[ks] = h;
    }
  }
  unsigned long long mb = 0;
  {
    const int* mrow = mask + b*L_ + z*KQ;
    #pragma unroll
    for (int j=0;j<64;++j)
      mb |= (unsigned long long)(mrow[j*16 + l16] ? 1u : 0u) << j;
  }

  f32x4 M = (f32x4){MINIT, MINIT, MINIT, MINIT};

  unsigned kof[4], vof[4], dof[4];
  #pragma unroll
  for (int i=0;i<4;++i){
    int c = (wave + i*4)*64 + lane;
    int r = c>>5, pk = c&31;
    kof[i] = (unsigned)(r*512 + ((pk ^ (r&7))*16));
    vof[i] = (unsigned)(c*16);
    dof[i] = (unsigned)((wave + i*4)*1024);
  }
  const char* kbase = (const char*)x16 + ((size_t)b*L_ + (size_t)z*KQ)*(D_*2);
  const char* vbase = (const char*)vtl + ((size_t)(b*64 + z*32))*16384;

  // prologue: K_0 only (V_0 is staged at the top of iter 0)
  #pragma unroll
  for (int i=0;i<4;++i) GLL(kbase + kof[i], (char*)sK[0] + dof[i]);

  f32x4 O[16], Osum;
  #pragma unroll
  for (int i=0;i<16;i++) O[i] = (f32x4){0.f,0.f,0.f,0.f};
  Osum = (f32x4){0.f,0.f,0.f,0.f};
  f16x8 ones;
  #pragma unroll
  for (int j=0;j<8;++j) ones[j] = (_Float16)1.0f;

  __syncthreads();   // K_0 visible

  for (int it=0; it<NIT; ++it){
    // ---- stage K_{t+1} and V_t ----
    if (it+1 < NIT){
      const char* kb2 = kbase + (size_t)(it+1)*16384;
      char* kd = (char*)sK[(it+1)&1];
      #pragma unroll
      for (int i=0;i<4;++i) GLL(kb2 + kof[i], kd + dof[i]);
    }
    {
      const char* vb2 = vbase + (size_t)it*16384;
      char* vd = (char*)sV[it&1];
      #pragma unroll
      for (int i=0;i<4;++i) GLL(vb2 + vof[i], vd + dof[i]);
    }
    const _Float16* kb = sK[it&1];

    // ---- S = Q·K^T (tile t, log2 domain) ----
    f32x4 S[2];
    S[0]=(f32x4){0,0,0,0}; S[1]=(f32x4){0,0,0,0};
    #pragma unroll
    for (int ks=0; ks<8; ++ks){
      f16x8 b0 = *(const f16x8*)(kb + (     l16)*256 + (((ks*4+quad)^sw)*8));
      f16x8 b1 = *(const f16x8*)(kb + (16 + l16)*256 + (((ks*4+quad)^sw)*8));
      S[0] = MFMA16F(qh[ks], b0, S[0]);
      S[1] = MFMA16F(qh[ks], b1, S[1]);
    }

    // ---- PV (tile t-1): operands ready since last barrier ----
    if (it > 0){
      const _Float16* vb = sV[(it-1)&1];
      f16x8 pf = *(const f16x8*)(&sP[(it-1)&1][wave][l16*PSTR + quad*8]);
      #pragma unroll
      for (int vt=0; vt<16; ++vt){
        f16x8 bv = *(const f16x8*)(vb + (vt*16+l16)*32 + ((quad^vsw)*8));
        O[vt] = MFMA16F(pf, bv, O[vt]);
      }
      Osum = MFMA16F(pf, ones, Osum);
    }

    // ---- diag zero (score 0 -> log2 score 0), then key padding mask ----
    {
      const int d0 = q0w - (z*KQ + it*BK);
      if ((unsigned)d0 < 32u){
        const int ntd = d0 >> 4;
        #pragma unroll
        for (int r=0;r<4;++r)
          S[ntd][r] = (l16 == quad*4+r) ? 0.0f : S[ntd][r];
      }
    }
    {
      const unsigned mw = (unsigned)(mb >> (unsigned)(it*2));
      const float mk0 = (mw & 1u) ? NEG_INF : 0.0f;
      const float mk1 = (mw & 2u) ? NEG_INF : 0.0f;
      #pragma unroll
      for (int r=0;r<4;++r){ S[0][r] += mk0; S[1][r] += mk1; }
    }

    // ---- defer-max check; rescale covers all tiles < t (PV t-1 done) ----
    {
      f32x4 t = fmax4(S[0], S[1]);
      int ok = 1;
      #pragma unroll
      for (int r=0;r<4;++r) ok &= (t[r] <= M[r] + THR);
      if (!__all(ok)){
        #pragma unroll
        for (int off=1; off<16; off<<=1){
          f32x4 o;
          o[0]=__shfl_xor(t[0],off); o[1]=__shfl_xor(t[1],off);
          o[2]=__shfl_xor(t[2],off); o[3]=__shfl_xor(t[3],off);
          t = fmax4(t,o);
        }
        f32x4 mn = fmax4(M, t);
        float sc[4];
        #pragma unroll
        for (int r=0;r<4;++r) sc[r] = exp2f(M[r] - mn[r]);
        #pragma unroll
        for (int vt=0; vt<16; ++vt){
          #pragma unroll
          for (int r=0;r<4;++r) O[vt][r] *= sc[r];
        }
        #pragma unroll
        for (int r=0;r<4;++r) Osum[r] *= sc[r];
        M = mn;
      }
    }

    // ---- P = 2^(S - M) -> sP[t&1]; consumed next iteration ----
    #pragma unroll
    for (int r=0;r<4;++r){
      const int row = quad*4 + r;
      sP[it&1][wave][row*PSTR +      l16] = (_Float16)exp2f(S[0][r] - M[r]);
      sP[it&1][wave][row*PSTR + 16 + l16] = (_Float16)exp2f(S[1][r] - M[r]);
    }

    __syncthreads();   // sP/sV(t) visible for t+1; staging drained
  }

  // ---- drain: PV for the last tile ----
  {
    const _Float16* vb = sV[(NIT-1)&1];
    f16x8 pf = *(const f16x8*)(&sP[(NIT-1)&1][wave][l16*PSTR + quad*8]);
    #pragma unroll
    for (int vt=0; vt<16; ++vt){
      f16x8 bv = *(const f16x8*)(vb + (vt*16+l16)*32 + ((quad^vsw)*8));
      O[vt] = MFMA16F(pf, bv, O[vt]);
    }
    Osum = MFMA16F(pf, ones, Osum);
  }

  // ---- epilogue: fragment-major fp16 partial O' + partial l + running m ----
  {
    const int u = b*(L_/16) + blockIdx.x*4 + wave;
    _Float16* ob = oall + (size_t)z*NE + (size_t)u*4096;
    #pragma unroll
    for (int vt=0; vt<16; ++vt){
      hf4 hh;
      #pragma unroll
      for (int r=0;r<4;++r) hh[r] = (_Float16)O[vt][r];
      *(hf4*)(ob + vt*256 + lane*4) = hh;
    }
    if (l16 == 0){
      const int row = u*16 + quad*4;
      #pragma unroll
      for (int r=0;r<4;++r){
        mll[z*NROW + row + r] = Osum[r];
        mm [z*NROW + row + r] = M[r];        // log2 domain
      }
    }
  }
}

// ---- combine: out = (sum_z 2^{m_z-m*} O'_z) / (sum_z 2^{m_z-m*} l_z) ----
__global__ void combine_k(float* __restrict__ out,
                          const _Float16* __restrict__ oall,
                          const float* __restrict__ mll,
                          const float* __restrict__ mm){
  __shared__ float T2[16][260];
  const int t = threadIdx.x, u = blockIdx.x;
  const int quad = (t>>4)&3, l16 = t&15;
  const int row0 = u*16 + quad*4;

  f32x4 mz[KSPLIT], lz[KSPLIT];
  #pragma unroll
  for (int zc=0; zc<KSPLIT; ++zc){
    mz[zc] = *(const f32x4*)(mm  + zc*NROW + row0);
    lz[zc] = *(const f32x4*)(mll + zc*NROW + row0);
  }
  f32x4 ms = mz[0];
  #pragma unroll
  for (int zc=1; zc<KSPLIT; ++zc) ms = fmax4(ms, mz[zc]);

  float sc[KSPLIT][4];
  f32x4 den = (f32x4){0.f,0.f,0.f,0.f};
  #pragma unroll
  for (int zc=0; zc<KSPLIT; ++zc){
    #pragma unroll
    for (int r=0;r<4;++r){
      sc[zc][r] = exp2f(mz[zc][r] - ms[r]);
      den[r] += sc[zc][r] * lz[zc][r];
    }
  }
  float inv[4];
  #pragma unroll
  for (int r=0;r<4;++r) inv[r] = 1.0f/den[r];

  #pragma unroll
  for (int i=0;i<4;++i){
    const int f = t + 256*i;
    const int vt = f>>6;
    float acc[4] = {0.f,0.f,0.f,0.f};
    #pragma unroll
    for (int zc=0; zc<KSPLIT; ++zc){
      hf4 v = *(const hf4*)(oall + (size_t)zc*NE + (size_t)u*4096 + (size_t)f*4);
      #pragma unroll
      for (int r=0;r<4;++r) acc[r] += sc[zc][r] * (float)v[r];
    }
    #pragma unroll
    for (int r=0;r<4;++r) T2[quad*4+r][vt*16+l16] = acc[r]*inv[r];
  }
  __syncthreads();
  #pragma unroll
  for (int p=0;p<4;++p){
    const int row = (t>>6) + p*4, col = (t&63)*4;
    float4 vv = *(const float4*)&T2[row][col];
    *(float4*)(out + ((size_t)u*16 + row)*D_ + col) = vv;
  }
}

extern "C" void kernel_launch(void* const* d_in, const int* in_sizes, int n_in,
                              void* d_out, int out_size, void* d_ws, size_t ws_size,
                              hipStream_t stream) {
  const float* x    = (const float*)d_in[0];
  const int*   mask = (const int*)d_in[1];
  float*       out  = (float*)d_out;

  _Float16* x16  = (_Float16*)d_ws;
  _Float16* vtl  = x16 + NE;
  _Float16* oall = vtl + NE;                       // KSPLIT*NE fp16
  float*    mll  = (float*)(oall + (size_t)KSPLIT*NE);
  float*    mm   = mll + (size_t)KSPLIT*NROW;

  prep_k   <<<dim3(L_/32, B_), dim3(256), 0, stream>>>(x, x16, vtl);
  flash_k  <<<dim3(L_/64, B_, KSPLIT), dim3(256), 0, stream>>>(x16, vtl, mask, oall, mll, mm);
  combine_k<<<dim3(NROW/16), dim3(256), 0, stream>>>(out, oall, mll, mm);
}